// Round 13
// baseline (2465.659 us; speedup 1.0000x reference)
//
#include <hip/hip_runtime.h>
#include <stdint.h>

#define BB 4
#define NN 16384
#define NPOINT 1024
#define NSAMPLE 32
#define CC 64
#define RADIUS2 0.00999999977648258209228515625f
#define BIGF 1.0e10f

#define FT 512     // threads per block (8 waves)
#define NPAIR 16   // fps point-pairs per thread (32 points/thread)
#define NCONS 128  // consumer blocks
#define NGRP 256   // 16-centroid groups (4096 centroids / 16)

typedef float f32x2 __attribute__((ext_vector_type(2)));

// ---------------- repack w1 (64x67) -> (64x68) padded, pad=0 ----------------
// Also zeroes the 256 group-ready flags (workspace may be poisoned).
__global__ __launch_bounds__(256) void repack_w1(const float* __restrict__ w1,
                                                 float* __restrict__ w1p,
                                                 int* __restrict__ flags) {
    int t = threadIdx.x;
    for (int i = t; i < 64 * 68; i += 256) {
        int o = i / 68, c = i % 68;
        w1p[i] = (c < 67) ? w1[o * 67 + c] : 0.0f;
    }
    flags[t] = 0;  // exactly NGRP entries
}

// DPP-based argmax step (max value, min index on ties) — validated bit-exact.
template <int CTRL>
__device__ __forceinline__ void amax_step(float& v, int& i) {
    int nv = __builtin_amdgcn_update_dpp(__float_as_int(v), __float_as_int(v),
                                         CTRL, 0xf, 0xf, false);
    int ni = __builtin_amdgcn_update_dpp(i, i, CTRL, 0xf, 0xf, false);
    float fv = __int_as_float(nv);
    if (fv > v || (fv == v && ni < i)) { v = fv; i = ni; }
}
// Payload variant: z rides along with the winning candidate. The selection
// predicate is identical, so the (max value, min index) result is unchanged;
// z is just the winner's third coordinate (exact bits).
template <int CTRL>
__device__ __forceinline__ void amax_step_p(float& v, int& i, float& z) {
    int nv = __builtin_amdgcn_update_dpp(__float_as_int(v), __float_as_int(v),
                                         CTRL, 0xf, 0xf, false);
    int ni = __builtin_amdgcn_update_dpp(i, i, CTRL, 0xf, 0xf, false);
    int nz = __builtin_amdgcn_update_dpp(__float_as_int(z), __float_as_int(z),
                                         CTRL, 0xf, 0xf, false);
    float fv = __int_as_float(nv);
    if (fv > v || (fv == v && ni < i)) { v = fv; i = ni; z = __int_as_float(nz); }
}
__device__ __forceinline__ void wave_amax_p(float& v, int& i, float& z) {
    amax_step_p<0x111>(v, i, z);  // row_shr:1
    amax_step_p<0x112>(v, i, z);  // row_shr:2
    amax_step_p<0x114>(v, i, z);  // row_shr:4
    amax_step_p<0x118>(v, i, z);  // row_shr:8
    amax_step_p<0x142>(v, i, z);  // row_bcast:15
    amax_step_p<0x143>(v, i, z);  // row_bcast:31  -> lane63 = wave winner
}

// ---------------- fused producer-consumer kernel ----------------
// R12 post-mortem: producer still +0.52us/iter vs standalone R8. Residual
// causes: (a) the per-iteration uniform global read cz=xb[ixs*3+2] sits on
// the serial chain and its latency triples when 128 consumer blocks stream
// xyz/features through L2/fabric; (b) the in-loop RELEASE drained the JUST-
// ISSUED group stores (vmcnt covers them -- R12's deferral was ordered
// wrong). R13: (1) z is carried through the argmax reduce as a DPP payload
// -> cz comes from readlane, x/y from the LDS planes: the producer loop
// touches ONLY VALU+LDS, so consumer traffic cannot inflate its chain.
// (2) at flush of group g: release flag g-1 FIRST (its stores completed
// ~27us ago -> vmcnt already 0 -> free), THEN store group g. Final flag
// after the loop. Consumers unchanged from validated R12.
__global__ __launch_bounds__(FT, 2)
void uber_kernel(const float* xyz, const float* features,
                 float* new_xyz, float* out,
                 const float* __restrict__ w1p, const float* __restrict__ b1,
                 const float* __restrict__ w2, const float* __restrict__ b2,
                 const float* __restrict__ w3, const float* __restrict__ b3,
                 int* flags) {
    __shared__ float sx[NN];            // 64 KB (fps winner x lookup)
    __shared__ float sy[NN];            // 64 KB (fps winner y lookup)
    __shared__ float4 svi[2][8];        // fps parity dbuf (v, idx, z, -)
    __shared__ float stg[48];           // rolling 16-centroid stash
    __shared__ int slist[16][NSAMPLE];  // 2 KB (consumer neighbor lists)

    const int t = threadIdx.x;
    const int lane = t & 63;

    if (blockIdx.x < BB) {
        // ======================= FPS producer ===============================
        const int b = blockIdx.x;
        const int w = t >> 6;  // 0..7
        const float* xb = xyz + (size_t)b * NN * 3;

        f32x2 px[NPAIR], py[NPAIR], pz[NPAIR], dd[NPAIR];

        // load + transpose: pair k covers points g = 2*(k*FT+t) and g+1
#pragma unroll
        for (int k = 0; k < NPAIR; ++k) {
            const float* p = xb + (size_t)6 * (k * FT + t);
            f32x2 a = *(const f32x2*)(p + 0);
            f32x2 bq = *(const f32x2*)(p + 2);
            f32x2 c = *(const f32x2*)(p + 4);
            int g = 2 * (k * FT + t);
            px[k].x = a.x;  py[k].x = a.y;  pz[k].x = bq.x;
            px[k].y = bq.y; py[k].y = c.x;  pz[k].y = c.y;
            *(f32x2*)&sx[g] = px[k];   // LDS copies for winner lookup
            *(f32x2*)&sy[g] = py[k];
            dd[k].x = BIGF; dd[k].y = BIGF;
        }
        // one-time non-volatile anchor (R8's exact form)
#pragma unroll
        for (int k = 0; k < NPAIR; ++k)
            asm("" : "+v"(px[k]), "+v"(py[k]), "+v"(pz[k]));

        float cx = xb[0], cy = xb[1], cz = xb[2];
        __syncthreads();

        for (int i = 0; i < NPOINT; ++i) {
            if (t == 0) {  // stash into rolling LDS slot (cheap, as R8)
                int sl = 3 * (i & 15);
                stg[sl + 0] = cx; stg[sl + 1] = cy; stg[sl + 2] = cz;
            }
            if ((i & 15) == 15 && w == 0) {
                int g16 = i >> 4;
                // release PREVIOUS group's flag first: its stores were issued
                // 16 iterations (~27us) ago, vmcnt is already drained -> the
                // release costs ~nothing and orders flag after those stores.
                if (lane == 0 && g16 > 0)
                    __hip_atomic_store(&flags[b * 64 + g16 - 1], 1,
                                       __ATOMIC_RELEASE, __HIP_MEMORY_SCOPE_AGENT);
                // then fire-and-forget this group's 48 coalesced stores
                if (lane < 48) {
                    float v = stg[lane];
                    new_xyz[((size_t)b * NPOINT + (size_t)g16 * 16) * 3 + lane] = v;
                }
            }
            if (i == NPOINT - 1) break;

            f32x2 c2x; c2x.x = cx; c2x.y = cx;
            f32x2 c2y; c2y.x = cy; c2y.y = cy;
            f32x2 c2z; c2z.x = cz; c2z.y = cz;

            // EXACT numpy semantics: sub; squares rounded individually; sum
            // (x^2+y^2)+z^2; min; exact max (no rounding).
            float mxx = -1.0f, mxy = -1.0f;
#pragma unroll
            for (int k = 0; k < NPAIR; ++k) {
                f32x2 dx = px[k] - c2x;
                f32x2 dy = py[k] - c2y;
                f32x2 dz = pz[k] - c2z;
                f32x2 m0 = dx * dx;
                f32x2 m1 = dy * dy;
                f32x2 m2 = dz * dz;
                f32x2 d  = (m0 + m1) + m2;
                dd[k].x = fminf(dd[k].x, d.x);
                dd[k].y = fminf(dd[k].y, d.y);
                mxx = fmaxf(mxx, dd[k].x);
                mxy = fmaxf(mxy, dd[k].y);
            }
            float bv = fmaxf(mxx, mxy);

            // first-occurrence scan also selects the winner's z (same
            // predicate chain -> selection unchanged, payload exact).
            int bj = 0;
            float wz = pz[0].x;
#pragma unroll
            for (int k = NPAIR - 1; k >= 0; --k) {
                if (dd[k].y == bv) { bj = 2 * k + 1; wz = pz[k].y; }
                if (dd[k].x == bv) { bj = 2 * k;     wz = pz[k].x; }
            }
            int bi = (bj >> 1) * (2 * FT) + 2 * t + (bj & 1);

            wave_amax_p(bv, bi, wz);
            if (lane == 63)
                svi[i & 1][w] = make_float4(bv, __int_as_float(bi), wz, 0.0f);
            __syncthreads();

            float4 s = svi[i & 1][lane & 7];
            float v2 = s.x;
            int i2 = __float_as_int(s.y);
            float z2 = s.z;
            amax_step_p<0x111>(v2, i2, z2);  // row_shr:1
            amax_step_p<0x112>(v2, i2, z2);  // row_shr:2
            amax_step_p<0x114>(v2, i2, z2);  // row_shr:4
            int ixs = __builtin_amdgcn_readlane(i2, 63);
            cz = __int_as_float(
                __builtin_amdgcn_readlane(__float_as_int(z2), 63));

            // winner x,y from LDS (exact copies); NO global access in loop
            cx = sx[ixs];
            cy = sy[ixs];
        }

        // final group's flag (group 63): after all its stores
        if (w == 0 && lane == 0)
            __hip_atomic_store(&flags[b * 64 + 63], 1,
                               __ATOMIC_RELEASE, __HIP_MEMORY_SCOPE_AGENT);
        return;
    }

    // ========================= consumer (R12 exact) =========================
    const int c = blockIdx.x - BB;         // 0..127
    int gA = c, gB = (NGRP - 1) - c;
    if ((gA & 63) > (gB & 63)) { int tq = gA; gA = gB; gB = tq; }  // early first

    for (int r = 0; r < 2; ++r) {
        const int g = (r == 0) ? gA : gB;
        const int base = g * 16;           // first cid of this group

        if (t == 0) {  // gentle bounded spin: RELAXED polls ~1.7us apart,
                       // one ACQUIRE load on success for ordering.
            int guard = 0;
            while (__hip_atomic_load(&flags[g], __ATOMIC_RELAXED,
                                     __HIP_MEMORY_SCOPE_AGENT) == 0) {
                if (++guard > (1 << 14)) break;  // ~28ms cap: no hang, ever
                __builtin_amdgcn_s_sleep(64);
            }
            (void)__hip_atomic_load(&flags[g], __ATOMIC_ACQUIRE,
                                    __HIP_MEMORY_SCOPE_AGENT);
        }
        __syncthreads();

        // ---- ball query (exact validated code): wave w does n=2w, 2w+1 ----
        const int w = t >> 6;
        for (int q = 0; q < 2; ++q) {
            const int n = 2 * w + q;
            const int cid = base + n;
            const int b_ = cid >> 10;
            const float* xb = xyz + (size_t)b_ * NN * 3;
            const float* cc = new_xyz + (size_t)cid * 3;
            float cx = cc[0], cy = cc[1], cz = cc[2];

            int cnt = 0;
            for (int bs = 0; bs < NN && cnt < NSAMPLE; bs += 64) {
                int j = bs + lane;
                float dx = __fsub_rn(xb[j * 3 + 0], cx);
                float dy = __fsub_rn(xb[j * 3 + 1], cy);
                float dz = __fsub_rn(xb[j * 3 + 2], cz);
                float d2 = __fadd_rn(__fadd_rn(__fmul_rn(dx, dx),
                                               __fmul_rn(dy, dy)),
                                     __fmul_rn(dz, dz));
                bool hit = d2 < RADIUS2;
                unsigned long long m = __ballot(hit);
                int pre = __popcll(m & ((1ull << lane) - 1ull));
                if (hit) {
                    int pos = cnt + pre;
                    if (pos < NSAMPLE) slist[n][pos] = j;
                }
                cnt += __popcll(m);  // uniform
            }
            if (lane < NSAMPLE) {  // pad in place (same-wave DS ops, ordered)
                int first = slist[n][0];  // centroid itself always hits
                int v = (lane < cnt) ? slist[n][lane] : first;
                slist[n][lane] = v;
            }
        }
        __syncthreads();

        // ---- mlp (exact validated code): thread = (centroid n, sample s) ---
        {
            const int n = t >> 5;
            const int s = t & 31;
            const int cid = base + n;
            const int b_ = cid >> 10;
            const int p = cid & 1023;
            const int idx = slist[n][s];

            const float* nc = new_xyz + (size_t)cid * 3;
            const float* pt = xyz + ((size_t)b_ * NN + idx) * 3;
            float gx = pt[0] - nc[0], gy = pt[1] - nc[1], gz = pt[2] - nc[2];

            float fin[64];
            const float4* fp =
                (const float4*)(features + ((size_t)b_ * NN + idx) * CC);
#pragma unroll
            for (int j = 0; j < 16; ++j) {
                float4 q = fp[j];
                fin[4 * j] = q.x; fin[4 * j + 1] = q.y;
                fin[4 * j + 2] = q.z; fin[4 * j + 3] = q.w;
            }

            float h1[64];
#pragma unroll
            for (int o = 0; o < 64; ++o) {
                const float4* wr = (const float4*)(w1p + o * 68);
                float acc = b1[o];
                float4 q0 = wr[0];
                acc = fmaf(q0.x, gx, acc);
                acc = fmaf(q0.y, gy, acc);
                acc = fmaf(q0.z, gz, acc);
                acc = fmaf(q0.w, fin[0], acc);
#pragma unroll
                for (int j = 1; j < 17; ++j) {
                    float4 q = wr[j];
                    int c0 = 4 * j - 3;
                    acc = fmaf(q.x, fin[c0], acc);
                    acc = fmaf(q.y, fin[c0 + 1], acc);
                    acc = fmaf(q.z, fin[c0 + 2], acc);
                    if (c0 + 3 < 64) acc = fmaf(q.w, fin[c0 + 3], acc);
                }
                h1[o] = fmaxf(acc, 0.0f);
            }

            float h2[64];
#pragma unroll
            for (int o = 0; o < 64; ++o) {
                const float4* wr = (const float4*)(w2 + o * 64);
                float acc = b2[o];
#pragma unroll
                for (int j = 0; j < 16; ++j) {
                    float4 q = wr[j];
                    acc = fmaf(q.x, h1[4 * j], acc);
                    acc = fmaf(q.y, h1[4 * j + 1], acc);
                    acc = fmaf(q.z, h1[4 * j + 2], acc);
                    acc = fmaf(q.w, h1[4 * j + 3], acc);
                }
                h2[o] = fmaxf(acc, 0.0f);
            }

            float* ob = out + (size_t)b_ * 128 * NPOINT + p;
#pragma unroll
            for (int o = 0; o < 128; ++o) {
                const float4* wr = (const float4*)(w3 + o * 64);
                float acc = b3[o];
#pragma unroll
                for (int j = 0; j < 16; ++j) {
                    float4 q = wr[j];
                    acc = fmaf(q.x, h2[4 * j], acc);
                    acc = fmaf(q.y, h2[4 * j + 1], acc);
                    acc = fmaf(q.z, h2[4 * j + 2], acc);
                    acc = fmaf(q.w, h2[4 * j + 3], acc);
                }
                float r2 = fmaxf(acc, 0.0f);
#pragma unroll
                for (int off = 1; off < 32; off <<= 1) {
                    float orr = __shfl_xor(r2, off);
                    r2 = fmaxf(r2, orr);
                }
                if (s == 0) ob[(size_t)o * NPOINT] = r2;
            }
        }
        __syncthreads();  // slist reused next round
    }
}

extern "C" void kernel_launch(void* const* d_in, const int* in_sizes, int n_in,
                              void* d_out, int out_size, void* d_ws, size_t ws_size,
                              hipStream_t stream) {
    const float* xyz = (const float*)d_in[0];
    const float* features = (const float*)d_in[1];
    const float* w1 = (const float*)d_in[2];
    const float* b1 = (const float*)d_in[3];
    const float* w2 = (const float*)d_in[4];
    const float* b2 = (const float*)d_in[5];
    const float* w3 = (const float*)d_in[6];
    const float* b3 = (const float*)d_in[7];

    float* out = (float*)d_out;
    float* new_xyz = out;                          // B*NPOINT*3
    float* new_feat = out + BB * NPOINT * 3;       // B*128*NPOINT

    float* w1p = (float*)d_ws;                                  // 64*68 floats
    int* flags = (int*)((char*)d_ws + 64 * 68 * sizeof(float)); // 256 ints

    hipLaunchKernelGGL(repack_w1, dim3(1), dim3(256), 0, stream, w1, w1p, flags);
    hipLaunchKernelGGL(uber_kernel, dim3(BB + NCONS), dim3(FT), 0, stream,
                       xyz, features, new_xyz, new_feat,
                       w1p, b1, w2, b2, w3, b3, flags);
}

// Round 14
// 2113.118 us; speedup vs baseline: 1.1668x; 1.1668x over previous
//
#include <hip/hip_runtime.h>
#include <stdint.h>

#define BB 4
#define NN 16384
#define NPOINT 1024
#define NSAMPLE 32
#define CC 64
#define RADIUS2 0.00999999977648258209228515625f
#define BIGF 1.0e10f

#define FT 512     // fps threads per block (8 waves, 2/SIMD, 256-VGPR budget)
#define NPAIR 16   // point-pairs per thread (32 points/thread)

typedef float f32x2 __attribute__((ext_vector_type(2)));

// ---------------- repack w1 (64x67) -> (64x68) padded, pad=0 ----------------
__global__ __launch_bounds__(256) void repack_w1(const float* __restrict__ w1,
                                                 float* __restrict__ w1p) {
    int t = threadIdx.x;
    for (int i = t; i < 64 * 68; i += 256) {
        int o = i / 68, c = i % 68;
        w1p[i] = (c < 67) ? w1[o * 67 + c] : 0.0f;
    }
}

// DPP-based argmax step (max value, min index on ties) — validated bit-exact.
template <int CTRL>
__device__ __forceinline__ void amax_step(float& v, int& i) {
    int nv = __builtin_amdgcn_update_dpp(__float_as_int(v), __float_as_int(v),
                                         CTRL, 0xf, 0xf, false);
    int ni = __builtin_amdgcn_update_dpp(i, i, CTRL, 0xf, 0xf, false);
    float fv = __int_as_float(nv);
    if (fv > v || (fv == v && ni < i)) { v = fv; i = ni; }
}
__device__ __forceinline__ void wave_amax(float& v, int& i) {
    amax_step<0x111>(v, i);  // row_shr:1
    amax_step<0x112>(v, i);  // row_shr:2
    amax_step<0x114>(v, i);  // row_shr:4
    amax_step<0x118>(v, i);  // row_shr:8
    amax_step<0x142>(v, i);  // row_bcast:15
    amax_step<0x143>(v, i);  // row_bcast:31  -> lane63 holds full wave result
}

// ---------------- FPS: one 512-thread block per batch ----------------
// FINAL CONFIG (best measured across 14 variants: fps 1730us, R8).
// Closed arms, with the evidence:
//  - register-residency family (R0/R2/R9/R10): allocator never holds the
//    128-float state regardless of anchor form; VGPR plateaus at 84-88.
//  - instruction-packing family (R4-pk vs R7-scalar vs R9-max3): identical.
//  - cross-CU FPS (R1/R6): ~1.8us/iter exchange latency floor.
//  - producer-consumer fusion (R11/R12/R13: 2795/2315/2405 vs 2197/2175
//    separate): producer stretches ~1.7->2.3ms whenever 128 consumer CUs
//    are active, even with ZERO producer global traffic (R13) -- consistent
//    with chip-wide clock reduction under load; tail (~380us) < interference.
// Structure: coords loaded to regs w/ one-time non-volatile anchor; x/y
// planes mirrored in LDS for the winner lookup; deferred argmax (running
// max + descending equality scan, bit-exact); 8-wave DPP reduce; LDS
// centroid stash dumped once, coalesced.
__global__ __launch_bounds__(FT, 2)
void fps_kernel(const float* xyz, float* new_xyz) {
    const int b = blockIdx.x;
    const int t = threadIdx.x;
    const int lane = t & 63;
    const int w = t >> 6;  // 0..7

    __shared__ float sx[NN];          // 64 KB (winner lookup only)
    __shared__ float sy[NN];          // 64 KB (winner lookup only)
    __shared__ float st[3 * NPOINT];  // 12 KB centroid stash
    __shared__ float2 svi[2][8];      // parity double-buffered (v, idx)

    const float* xb = xyz + (size_t)b * NN * 3;

    f32x2 px[NPAIR], py[NPAIR], pz[NPAIR], dd[NPAIR];

    // load + transpose: pair k covers points g = 2*(k*FT+t) and g+1
#pragma unroll
    for (int k = 0; k < NPAIR; ++k) {
        const float* p = xb + (size_t)6 * (k * FT + t);
        f32x2 a = *(const f32x2*)(p + 0);
        f32x2 bq = *(const f32x2*)(p + 2);
        f32x2 c = *(const f32x2*)(p + 4);
        int g = 2 * (k * FT + t);
        px[k].x = a.x;  py[k].x = a.y;  pz[k].x = bq.x;
        px[k].y = bq.y; py[k].y = c.x;  pz[k].y = c.y;
        *(f32x2*)&sx[g] = px[k];   // LDS copies for winner lookup
        *(f32x2*)&sy[g] = py[k];
        dd[k].x = BIGF; dd[k].y = BIGF;
    }
    // one-time non-volatile anchor (R8's exact form)
#pragma unroll
    for (int k = 0; k < NPAIR; ++k)
        asm("" : "+v"(px[k]), "+v"(py[k]), "+v"(pz[k]));

    // initial centroid = point 0
    float cx = xb[0], cy = xb[1], cz = xb[2];
    __syncthreads();

    for (int i = 0; i < NPOINT; ++i) {
        if (t == 0) {  // stash centroid in LDS; dumped to global after loop
            st[3 * i + 0] = cx; st[3 * i + 1] = cy; st[3 * i + 2] = cz;
        }
        if (i == NPOINT - 1) break;  // last centroid stashed; no next needed

        f32x2 c2x; c2x.x = cx; c2x.y = cx;
        f32x2 c2y; c2y.x = cy; c2y.y = cy;
        f32x2 c2z; c2z.x = cz; c2z.y = cz;

        // ---- packed distance update + running max (no index tracking) ----
        // EXACT numpy semantics per element: sub; products rounded
        // individually; sum order (x^2+y^2)+z^2; min. Max is exact.
        float mxx = -1.0f, mxy = -1.0f;
#pragma unroll
        for (int k = 0; k < NPAIR; ++k) {
            f32x2 dx = px[k] - c2x;       // v_pk_add_f32 (neg)
            f32x2 dy = py[k] - c2y;
            f32x2 dz = pz[k] - c2z;
            f32x2 m0 = dx * dx;           // v_pk_mul_f32
            f32x2 m1 = dy * dy;
            f32x2 m2 = dz * dz;
            f32x2 d  = (m0 + m1) + m2;    // v_pk_add_f32 x2
            dd[k].x = fminf(dd[k].x, d.x);
            dd[k].y = fminf(dd[k].y, d.y);
            mxx = fmaxf(mxx, dd[k].x);
            mxy = fmaxf(mxy, dd[k].y);
        }
        float bv = fmaxf(mxx, mxy);  // exact max of all 32 dd values

        // first-occurrence index: descending overwrite scan; .y before .x so
        // lower (k,e) wins. bv matches at least one slot by construction.
        int bj = 0;
#pragma unroll
        for (int k = NPAIR - 1; k >= 0; --k) {
            if (dd[k].y == bv) bj = 2 * k + 1;
            if (dd[k].x == bv) bj = 2 * k;
        }
        // global index: g = (bj>>1)*2*FT + 2*t + (bj&1); monotone in (k,e)
        // for fixed t -> in-thread first-occurrence holds
        int bi = (bj >> 1) * (2 * FT) + 2 * t + (bj & 1);

        wave_amax(bv, bi);
        if (lane == 63) svi[i & 1][w] = make_float2(bv, __int_as_float(bi));
        __syncthreads();

        // each lane reads ONE of the 8 wave slots; lanes 56..63 cover slots
        // 0..7, so 3 row_shr steps make lane63 the full block reduction.
        float2 s = svi[i & 1][lane & 7];
        float v2 = s.x;
        int i2 = __float_as_int(s.y);
        amax_step<0x111>(v2, i2);  // row_shr:1
        amax_step<0x112>(v2, i2);  // row_shr:2
        amax_step<0x114>(v2, i2);  // row_shr:4
        int ixs = __builtin_amdgcn_readlane(i2, 63);  // uniform -> SGPR

        // next centroid: x,y from LDS (exact copies), z via uniform global
        cx = sx[ixs];
        cy = sy[ixs];
        cz = xb[ixs * 3 + 2];
    }

    // dump stash -> global, coalesced (6 stores/thread)
    __syncthreads();
    float* ob = new_xyz + (size_t)b * NPOINT * 3;
    for (int j = t; j < 3 * NPOINT; j += FT) ob[j] = st[j];
}

// ---------------- ball query: one wave per centroid ----------------
__global__ __launch_bounds__(256) void ballquery_kernel(const float* __restrict__ xyz,
                                                        const float* __restrict__ new_xyz,
                                                        int* __restrict__ nidx) {
    const int t = threadIdx.x;
    const int lane = t & 63;
    const int w = t >> 6;
    const int cid = blockIdx.x * 4 + w;  // 0..4095
    const int b = cid >> 10;

    __shared__ int list[4][NSAMPLE];

    const float* xb = xyz + (size_t)b * NN * 3;
    const float* c = new_xyz + (size_t)cid * 3;
    float cx = c[0], cy = c[1], cz = c[2];

    int cnt = 0;
    for (int base = 0; base < NN && cnt < NSAMPLE; base += 64) {
        int j = base + lane;
        float dx = __fsub_rn(xb[j * 3 + 0], cx);
        float dy = __fsub_rn(xb[j * 3 + 1], cy);
        float dz = __fsub_rn(xb[j * 3 + 2], cz);
        float d2 = __fadd_rn(__fadd_rn(__fmul_rn(dx, dx), __fmul_rn(dy, dy)),
                             __fmul_rn(dz, dz));
        bool hit = d2 < RADIUS2;
        unsigned long long m = __ballot(hit);
        int pre = __popcll(m & ((1ull << lane) - 1ull));
        if (hit) {
            int pos = cnt + pre;
            if (pos < NSAMPLE) list[w][pos] = j;
        }
        cnt += __popcll(m);  // ballot result uniform -> cnt stays wave-uniform
    }
    __syncthreads();
    if (lane < NSAMPLE) {
        int first = list[w][0];  // >=1 hit always: centroid is a member point
        int v = (lane < cnt) ? list[w][lane] : first;
        nidx[(size_t)cid * NSAMPLE + lane] = v;
    }
}

// ---------------- grouped MLP + maxpool: one thread per (point,sample) ------
__global__ __launch_bounds__(256, 2) void mlp_kernel(
    const float* __restrict__ xyz, const float* __restrict__ features,
    const float* __restrict__ new_xyz, const int* __restrict__ nidx,
    const float* __restrict__ w1p, const float* __restrict__ b1,
    const float* __restrict__ w2, const float* __restrict__ b2,
    const float* __restrict__ w3, const float* __restrict__ b3,
    float* __restrict__ out) {
    const int gid = blockIdx.x * 256 + threadIdx.x;
    const int s = gid & 31;
    const int pg = gid >> 5;  // b*1024 + p
    const int b = pg >> 10;
    const int p = pg & 1023;

    const int idx = nidx[gid];
    const float* nc = new_xyz + (size_t)pg * 3;
    const float* pt = xyz + ((size_t)b * NN + idx) * 3;
    float gx = pt[0] - nc[0], gy = pt[1] - nc[1], gz = pt[2] - nc[2];

    float fin[64];
    const float4* fp = (const float4*)(features + ((size_t)b * NN + idx) * CC);
#pragma unroll
    for (int j = 0; j < 16; ++j) {
        float4 q = fp[j];
        fin[4 * j] = q.x; fin[4 * j + 1] = q.y;
        fin[4 * j + 2] = q.z; fin[4 * j + 3] = q.w;
    }

    float h1[64];
#pragma unroll
    for (int o = 0; o < 64; ++o) {
        const float4* wr = (const float4*)(w1p + o * 68);  // uniform -> s_load
        float acc = b1[o];
        float4 q0 = wr[0];
        acc = fmaf(q0.x, gx, acc);
        acc = fmaf(q0.y, gy, acc);
        acc = fmaf(q0.z, gz, acc);
        acc = fmaf(q0.w, fin[0], acc);
#pragma unroll
        for (int j = 1; j < 17; ++j) {
            float4 q = wr[j];
            int c0 = 4 * j - 3;
            acc = fmaf(q.x, fin[c0], acc);
            acc = fmaf(q.y, fin[c0 + 1], acc);
            acc = fmaf(q.z, fin[c0 + 2], acc);
            if (c0 + 3 < 64) acc = fmaf(q.w, fin[c0 + 3], acc);
        }
        h1[o] = fmaxf(acc, 0.0f);
    }

    float h2[64];
#pragma unroll
    for (int o = 0; o < 64; ++o) {
        const float4* wr = (const float4*)(w2 + o * 64);
        float acc = b2[o];
#pragma unroll
        for (int j = 0; j < 16; ++j) {
            float4 q = wr[j];
            acc = fmaf(q.x, h1[4 * j], acc);
            acc = fmaf(q.y, h1[4 * j + 1], acc);
            acc = fmaf(q.z, h1[4 * j + 2], acc);
            acc = fmaf(q.w, h1[4 * j + 3], acc);
        }
        h2[o] = fmaxf(acc, 0.0f);
    }

    float* ob = out + (size_t)b * 128 * NPOINT + p;
#pragma unroll
    for (int o = 0; o < 128; ++o) {
        const float4* wr = (const float4*)(w3 + o * 64);
        float acc = b3[o];
#pragma unroll
        for (int j = 0; j < 16; ++j) {
            float4 q = wr[j];
            acc = fmaf(q.x, h2[4 * j], acc);
            acc = fmaf(q.y, h2[4 * j + 1], acc);
            acc = fmaf(q.z, h2[4 * j + 2], acc);
            acc = fmaf(q.w, h2[4 * j + 3], acc);
        }
        float r = fmaxf(acc, 0.0f);
#pragma unroll
        for (int off = 1; off < 32; off <<= 1) {
            float orr = __shfl_xor(r, off);
            r = fmaxf(r, orr);
        }
        if (s == 0) ob[(size_t)o * NPOINT] = r;
    }
}

extern "C" void kernel_launch(void* const* d_in, const int* in_sizes, int n_in,
                              void* d_out, int out_size, void* d_ws, size_t ws_size,
                              hipStream_t stream) {
    const float* xyz = (const float*)d_in[0];
    const float* features = (const float*)d_in[1];
    const float* w1 = (const float*)d_in[2];
    const float* b1 = (const float*)d_in[3];
    const float* w2 = (const float*)d_in[4];
    const float* b2 = (const float*)d_in[5];
    const float* w3 = (const float*)d_in[6];
    const float* b3 = (const float*)d_in[7];

    float* out = (float*)d_out;
    float* new_xyz = out;                          // B*NPOINT*3
    float* new_feat = out + BB * NPOINT * 3;       // B*128*NPOINT

    int* nidx = (int*)d_ws;                        // B*NPOINT*NSAMPLE ints
    float* w1p = (float*)((char*)d_ws + (size_t)BB * NPOINT * NSAMPLE * sizeof(int));

    hipLaunchKernelGGL(repack_w1, dim3(1), dim3(256), 0, stream, w1, w1p);
    hipLaunchKernelGGL(fps_kernel, dim3(BB), dim3(FT), 0, stream, xyz, new_xyz);
    hipLaunchKernelGGL(ballquery_kernel, dim3(BB * NPOINT / 4), dim3(256), 0, stream,
                       xyz, new_xyz, nidx);
    hipLaunchKernelGGL(mlp_kernel, dim3(BB * NPOINT * NSAMPLE / 256), dim3(256), 0, stream,
                       xyz, features, new_xyz, nidx, w1p, b1, w2, b2, w3, b3, new_feat);
}

// Round 15
// 2031.692 us; speedup vs baseline: 1.2136x; 1.0401x over previous
//
#include <hip/hip_runtime.h>
#include <stdint.h>

#define BB 4
#define NN 16384
#define NPOINT 1024
#define NSAMPLE 32
#define CC 64
#define RADIUS2 0.00999999977648258209228515625f
#define BIGF 1.0e10f

#define FT 512     // fps threads per block (8 waves, 2/SIMD)
#define NPAIR 16   // point-pairs per thread (32 points/thread)

typedef float f32x2 __attribute__((ext_vector_type(2)));

// ---------------- repack w1 (64x67) -> (64x68) padded, pad=0 ----------------
__global__ __launch_bounds__(256) void repack_w1(const float* __restrict__ w1,
                                                 float* __restrict__ w1p) {
    int t = threadIdx.x;
    for (int i = t; i < 64 * 68; i += 256) {
        int o = i / 68, c = i % 68;
        w1p[i] = (c < 67) ? w1[o * 67 + c] : 0.0f;
    }
}

// DPP-based argmax step (max value, min index on ties) — validated bit-exact.
template <int CTRL>
__device__ __forceinline__ void amax_step(float& v, int& i) {
    int nv = __builtin_amdgcn_update_dpp(__float_as_int(v), __float_as_int(v),
                                         CTRL, 0xf, 0xf, false);
    int ni = __builtin_amdgcn_update_dpp(i, i, CTRL, 0xf, 0xf, false);
    float fv = __int_as_float(nv);
    if (fv > v || (fv == v && ni < i)) { v = fv; i = ni; }
}
__device__ __forceinline__ void wave_amax(float& v, int& i) {
    amax_step<0x111>(v, i);  // row_shr:1
    amax_step<0x112>(v, i);  // row_shr:2
    amax_step<0x114>(v, i);  // row_shr:4
    amax_step<0x118>(v, i);  // row_shr:8
    amax_step<0x142>(v, i);  // row_bcast:15
    amax_step<0x143>(v, i);  // row_bcast:31  -> lane63 holds full wave result
}

// ---------------- FPS: one 512-thread block per batch (FROZEN, R8) ---------
// Best of 15 rounds: 1730us, re-validated twice. Closed arms: register
// residency (R0/R2/R9/R10), instruction packing (R4/R7/R9), cross-CU
// exchange (R1/R6), producer-consumer fusion (R11-R13). Do not touch.
__global__ __launch_bounds__(FT, 2)
void fps_kernel(const float* xyz, float* new_xyz) {
    const int b = blockIdx.x;
    const int t = threadIdx.x;
    const int lane = t & 63;
    const int w = t >> 6;  // 0..7

    __shared__ float sx[NN];          // 64 KB (winner lookup only)
    __shared__ float sy[NN];          // 64 KB (winner lookup only)
    __shared__ float st[3 * NPOINT];  // 12 KB centroid stash
    __shared__ float2 svi[2][8];      // parity double-buffered (v, idx)

    const float* xb = xyz + (size_t)b * NN * 3;

    f32x2 px[NPAIR], py[NPAIR], pz[NPAIR], dd[NPAIR];

    // load + transpose: pair k covers points g = 2*(k*FT+t) and g+1
#pragma unroll
    for (int k = 0; k < NPAIR; ++k) {
        const float* p = xb + (size_t)6 * (k * FT + t);
        f32x2 a = *(const f32x2*)(p + 0);
        f32x2 bq = *(const f32x2*)(p + 2);
        f32x2 c = *(const f32x2*)(p + 4);
        int g = 2 * (k * FT + t);
        px[k].x = a.x;  py[k].x = a.y;  pz[k].x = bq.x;
        px[k].y = bq.y; py[k].y = c.x;  pz[k].y = c.y;
        *(f32x2*)&sx[g] = px[k];   // LDS copies for winner lookup
        *(f32x2*)&sy[g] = py[k];
        dd[k].x = BIGF; dd[k].y = BIGF;
    }
    // one-time non-volatile anchor (R8's exact form)
#pragma unroll
    for (int k = 0; k < NPAIR; ++k)
        asm("" : "+v"(px[k]), "+v"(py[k]), "+v"(pz[k]));

    // initial centroid = point 0
    float cx = xb[0], cy = xb[1], cz = xb[2];
    __syncthreads();

    for (int i = 0; i < NPOINT; ++i) {
        if (t == 0) {  // stash centroid in LDS; dumped to global after loop
            st[3 * i + 0] = cx; st[3 * i + 1] = cy; st[3 * i + 2] = cz;
        }
        if (i == NPOINT - 1) break;  // last centroid stashed; no next needed

        f32x2 c2x; c2x.x = cx; c2x.y = cx;
        f32x2 c2y; c2y.x = cy; c2y.y = cy;
        f32x2 c2z; c2z.x = cz; c2z.y = cz;

        // ---- packed distance update + running max (no index tracking) ----
        // EXACT numpy semantics per element: sub; products rounded
        // individually; sum order (x^2+y^2)+z^2; min. Max is exact.
        float mxx = -1.0f, mxy = -1.0f;
#pragma unroll
        for (int k = 0; k < NPAIR; ++k) {
            f32x2 dx = px[k] - c2x;       // v_pk_add_f32 (neg)
            f32x2 dy = py[k] - c2y;
            f32x2 dz = pz[k] - c2z;
            f32x2 m0 = dx * dx;           // v_pk_mul_f32
            f32x2 m1 = dy * dy;
            f32x2 m2 = dz * dz;
            f32x2 d  = (m0 + m1) + m2;    // v_pk_add_f32 x2
            dd[k].x = fminf(dd[k].x, d.x);
            dd[k].y = fminf(dd[k].y, d.y);
            mxx = fmaxf(mxx, dd[k].x);
            mxy = fmaxf(mxy, dd[k].y);
        }
        float bv = fmaxf(mxx, mxy);  // exact max of all 32 dd values

        // first-occurrence index: descending overwrite scan; .y before .x so
        // lower (k,e) wins. bv matches at least one slot by construction.
        int bj = 0;
#pragma unroll
        for (int k = NPAIR - 1; k >= 0; --k) {
            if (dd[k].y == bv) bj = 2 * k + 1;
            if (dd[k].x == bv) bj = 2 * k;
        }
        // global index: g = (bj>>1)*2*FT + 2*t + (bj&1); monotone in (k,e)
        // for fixed t -> in-thread first-occurrence holds
        int bi = (bj >> 1) * (2 * FT) + 2 * t + (bj & 1);

        wave_amax(bv, bi);
        if (lane == 63) svi[i & 1][w] = make_float2(bv, __int_as_float(bi));
        __syncthreads();

        // each lane reads ONE of the 8 wave slots; lanes 56..63 cover slots
        // 0..7, so 3 row_shr steps make lane63 the full block reduction.
        float2 s = svi[i & 1][lane & 7];
        float v2 = s.x;
        int i2 = __float_as_int(s.y);
        amax_step<0x111>(v2, i2);  // row_shr:1
        amax_step<0x112>(v2, i2);  // row_shr:2
        amax_step<0x114>(v2, i2);  // row_shr:4
        int ixs = __builtin_amdgcn_readlane(i2, 63);  // uniform -> SGPR

        // next centroid: x,y from LDS (exact copies), z via uniform global
        cx = sx[ixs];
        cy = sy[ixs];
        cz = xb[ixs * 3 + 2];
    }

    // dump stash -> global, coalesced (6 stores/thread)
    __syncthreads();
    float* ob = new_xyz + (size_t)b * NPOINT * 3;
    for (int j = t; j < 3 * NPOINT; j += FT) ob[j] = st[j];
}

// ---------------- ball query: one wave per centroid (FROZEN) ----------------
__global__ __launch_bounds__(256) void ballquery_kernel(const float* __restrict__ xyz,
                                                        const float* __restrict__ new_xyz,
                                                        int* __restrict__ nidx) {
    const int t = threadIdx.x;
    const int lane = t & 63;
    const int w = t >> 6;
    const int cid = blockIdx.x * 4 + w;  // 0..4095
    const int b = cid >> 10;

    __shared__ int list[4][NSAMPLE];

    const float* xb = xyz + (size_t)b * NN * 3;
    const float* c = new_xyz + (size_t)cid * 3;
    float cx = c[0], cy = c[1], cz = c[2];

    int cnt = 0;
    for (int base = 0; base < NN && cnt < NSAMPLE; base += 64) {
        int j = base + lane;
        float dx = __fsub_rn(xb[j * 3 + 0], cx);
        float dy = __fsub_rn(xb[j * 3 + 1], cy);
        float dz = __fsub_rn(xb[j * 3 + 2], cz);
        float d2 = __fadd_rn(__fadd_rn(__fmul_rn(dx, dx), __fmul_rn(dy, dy)),
                             __fmul_rn(dz, dz));
        bool hit = d2 < RADIUS2;
        unsigned long long m = __ballot(hit);
        int pre = __popcll(m & ((1ull << lane) - 1ull));
        if (hit) {
            int pos = cnt + pre;
            if (pos < NSAMPLE) list[w][pos] = j;
        }
        cnt += __popcll(m);  // ballot result uniform -> cnt stays wave-uniform
    }
    __syncthreads();
    if (lane < NSAMPLE) {
        int first = list[w][0];  // >=1 hit always: centroid is a member point
        int v = (lane < cnt) ? list[w][lane] : first;
        nidx[(size_t)cid * NSAMPLE + lane] = v;
    }
}

// ---------------- grouped MLP + maxpool: LDS-staged weights ----------------
// R15 theory: tail arithmetic pins mlp at ~300us vs a ~35us issue floor.
// Candidate mechanism: ~4160 uniform-address 16B weight loads per thread
// (s_load or VMEM) serialize on lgkmcnt/vmcnt at the end of each unrolled
// accumulate chain; 2 waves/SIMD can't hide it. Fix: stage ALL weights
// (w1p+w2+w3+biases = 67.6 KB) into LDS once per block (coalesced), then
// read via ds_read_b128 at wave-uniform addresses (broadcast, conflict-free,
// ~120cy pipelined -- hidden by the 17-deep fma chains). Same values, same
// fma order -> bit-exact. 67.6 KB LDS still allows 2 blocks/CU.
__global__ __launch_bounds__(256, 2) void mlp_kernel(
    const float* __restrict__ xyz, const float* __restrict__ features,
    const float* __restrict__ new_xyz, const int* __restrict__ nidx,
    const float* __restrict__ w1p, const float* __restrict__ b1,
    const float* __restrict__ w2, const float* __restrict__ b2,
    const float* __restrict__ w3, const float* __restrict__ b3,
    float* __restrict__ out) {
    __shared__ float sw1[64 * 68];   // 17 KB
    __shared__ float sw2[64 * 64];   // 16 KB
    __shared__ float sw3[128 * 64];  // 32 KB
    __shared__ float sb1[64];
    __shared__ float sb2[64];
    __shared__ float sb3[128];

    const int t = threadIdx.x;
    // coalesced one-time stage (vector where layouts allow)
    for (int i = t; i < 64 * 68 / 4; i += 256)
        ((float4*)sw1)[i] = ((const float4*)w1p)[i];
    for (int i = t; i < 64 * 64 / 4; i += 256)
        ((float4*)sw2)[i] = ((const float4*)w2)[i];
    for (int i = t; i < 128 * 64 / 4; i += 256)
        ((float4*)sw3)[i] = ((const float4*)w3)[i];
    if (t < 64)  { sb1[t] = b1[t]; sb2[t] = b2[t]; }
    if (t < 128) sb3[t] = b3[t];

    const int gid = blockIdx.x * 256 + t;
    const int s = gid & 31;
    const int pg = gid >> 5;  // b*1024 + p
    const int b = pg >> 10;
    const int p = pg & 1023;

    const int idx = nidx[gid];
    const float* nc = new_xyz + (size_t)pg * 3;
    const float* pt = xyz + ((size_t)b * NN + idx) * 3;
    float gx = pt[0] - nc[0], gy = pt[1] - nc[1], gz = pt[2] - nc[2];

    float fin[64];
    const float4* fp = (const float4*)(features + ((size_t)b * NN + idx) * CC);
#pragma unroll
    for (int j = 0; j < 16; ++j) {
        float4 q = fp[j];
        fin[4 * j] = q.x; fin[4 * j + 1] = q.y;
        fin[4 * j + 2] = q.z; fin[4 * j + 3] = q.w;
    }
    __syncthreads();  // weights staged

    float h1[64];
#pragma unroll
    for (int o = 0; o < 64; ++o) {
        const float4* wr = (const float4*)(sw1 + o * 68);  // uniform ds_read
        float acc = sb1[o];
        float4 q0 = wr[0];
        acc = fmaf(q0.x, gx, acc);
        acc = fmaf(q0.y, gy, acc);
        acc = fmaf(q0.z, gz, acc);
        acc = fmaf(q0.w, fin[0], acc);
#pragma unroll
        for (int j = 1; j < 17; ++j) {
            float4 q = wr[j];
            int c0 = 4 * j - 3;
            acc = fmaf(q.x, fin[c0], acc);
            acc = fmaf(q.y, fin[c0 + 1], acc);
            acc = fmaf(q.z, fin[c0 + 2], acc);
            if (c0 + 3 < 64) acc = fmaf(q.w, fin[c0 + 3], acc);
        }
        h1[o] = fmaxf(acc, 0.0f);
    }

    float h2[64];
#pragma unroll
    for (int o = 0; o < 64; ++o) {
        const float4* wr = (const float4*)(sw2 + o * 64);
        float acc = sb2[o];
#pragma unroll
        for (int j = 0; j < 16; ++j) {
            float4 q = wr[j];
            acc = fmaf(q.x, h1[4 * j], acc);
            acc = fmaf(q.y, h1[4 * j + 1], acc);
            acc = fmaf(q.z, h1[4 * j + 2], acc);
            acc = fmaf(q.w, h1[4 * j + 3], acc);
        }
        h2[o] = fmaxf(acc, 0.0f);
    }

    float* ob = out + (size_t)b * 128 * NPOINT + p;
#pragma unroll
    for (int o = 0; o < 128; ++o) {
        const float4* wr = (const float4*)(sw3 + o * 64);
        float acc = sb3[o];
#pragma unroll
        for (int j = 0; j < 16; ++j) {
            float4 q = wr[j];
            acc = fmaf(q.x, h2[4 * j], acc);
            acc = fmaf(q.y, h2[4 * j + 1], acc);
            acc = fmaf(q.z, h2[4 * j + 2], acc);
            acc = fmaf(q.w, h2[4 * j + 3], acc);
        }
        float r = fmaxf(acc, 0.0f);
#pragma unroll
        for (int off = 1; off < 32; off <<= 1) {
            float orr = __shfl_xor(r, off);
            r = fmaxf(r, orr);
        }
        if (s == 0) ob[(size_t)o * NPOINT] = r;
    }
}

extern "C" void kernel_launch(void* const* d_in, const int* in_sizes, int n_in,
                              void* d_out, int out_size, void* d_ws, size_t ws_size,
                              hipStream_t stream) {
    const float* xyz = (const float*)d_in[0];
    const float* features = (const float*)d_in[1];
    const float* w1 = (const float*)d_in[2];
    const float* b1 = (const float*)d_in[3];
    const float* w2 = (const float*)d_in[4];
    const float* b2 = (const float*)d_in[5];
    const float* w3 = (const float*)d_in[6];
    const float* b3 = (const float*)d_in[7];

    float* out = (float*)d_out;
    float* new_xyz = out;                          // B*NPOINT*3
    float* new_feat = out + BB * NPOINT * 3;       // B*128*NPOINT

    int* nidx = (int*)d_ws;                        // B*NPOINT*NSAMPLE ints
    float* w1p = (float*)((char*)d_ws + (size_t)BB * NPOINT * NSAMPLE * sizeof(int));

    hipLaunchKernelGGL(repack_w1, dim3(1), dim3(256), 0, stream, w1, w1p);
    hipLaunchKernelGGL(fps_kernel, dim3(BB), dim3(FT), 0, stream, xyz, new_xyz);
    hipLaunchKernelGGL(ballquery_kernel, dim3(BB * NPOINT / 4), dim3(256), 0, stream,
                       xyz, new_xyz, nidx);
    hipLaunchKernelGGL(mlp_kernel, dim3(BB * NPOINT * NSAMPLE / 256), dim3(256), 0, stream,
                       xyz, features, new_xyz, nidx, w1p, b1, w2, b2, w3, b3, new_feat);
}